// Round 2
// baseline (1692.317 us; speedup 1.0000x reference)
//
#include <hip/hip_runtime.h>

#define S 2048
#define F 1024
#define H 16
#define DH 64
#define NH (H * DH)   // 1024
#define PAD 68        // LDS row stride (floats) to break stride-64 bank alignment

// ---------------------------------------------------------------------------
// GEMM: C[M,N] = A[M,K] * W[K,N] + bias[N]   (fp32, BM=BN=64, BK=16, 4x4/thread)
// ---------------------------------------------------------------------------
__global__ __launch_bounds__(256) void gemm_bias(
    const float* __restrict__ A, const float* __restrict__ W,
    const float* __restrict__ bias, float* __restrict__ C,
    int M, int N, int K) {
  __shared__ float As[16][64];  // [k][m]
  __shared__ float Bs[16][64];  // [k][n]
  const int tid = threadIdx.x;
  const int tx = tid & 15, ty = tid >> 4;
  const int m0 = blockIdx.y * 64, n0 = blockIdx.x * 64;

  float acc[4][4] = {};

  for (int k0 = 0; k0 < K; k0 += 16) {
    // A tile: 64 rows x 16 cols -> As[col][row]
    {
      const int l = tid * 4;               // 0..1023
      const int row = l >> 4;              // 0..63
      const int col = l & 15;              // 0,4,8,12
      const float4 a = *(const float4*)(A + (m0 + row) * K + k0 + col);
      As[col + 0][row] = a.x;
      As[col + 1][row] = a.y;
      As[col + 2][row] = a.z;
      As[col + 3][row] = a.w;
    }
    // W tile: 16 rows x 64 cols -> Bs[row][col]
    {
      const int l = tid * 4;
      const int row = l >> 6;              // 0..15
      const int col = l & 63;              // 0..60 step 4
      *(float4*)&Bs[row][col] = *(const float4*)(W + (k0 + row) * N + n0 + col);
    }
    __syncthreads();
#pragma unroll
    for (int kk = 0; kk < 16; ++kk) {
      const float4 av = *(const float4*)&As[kk][ty * 4];
      const float4 bv = *(const float4*)&Bs[kk][tx * 4];
      const float ar[4] = {av.x, av.y, av.z, av.w};
      const float br[4] = {bv.x, bv.y, bv.z, bv.w};
#pragma unroll
      for (int r = 0; r < 4; ++r)
#pragma unroll
        for (int c = 0; c < 4; ++c) acc[r][c] += ar[r] * br[c];
    }
    __syncthreads();
  }

  const float4 bv = *(const float4*)(bias + n0 + tx * 4);
#pragma unroll
  for (int r = 0; r < 4; ++r) {
    const int row = m0 + ty * 4 + r;
    float4 o;
    o.x = acc[r][0] + bv.x;
    o.y = acc[r][1] + bv.y;
    o.z = acc[r][2] + bv.z;
    o.w = acc[r][3] + bv.w;
    *(float4*)(C + row * N + n0 + tx * 4) = o;
  }
}

// ---------------------------------------------------------------------------
// Fused flash-style rel-attention.
// Block = (i-tile of 64 queries, head). 256 threads, 4x4 microtiles.
// score[i,j] = ( (q[i]+rwb)·k[j] + (q[i]+rrb)·rkey[S-1-(i-j)] ) / 8,  j <= i
// ---------------------------------------------------------------------------
__global__ __launch_bounds__(256) void attn_kernel(
    const float* __restrict__ q, const float* __restrict__ k,
    const float* __restrict__ v, const float* __restrict__ rk,
    const float* __restrict__ rwb, const float* __restrict__ rrb,
    float* __restrict__ o) {
  __shared__ float Qw[64][PAD];
  __shared__ float Qr[64][PAD];
  __shared__ float KV[64][PAD];   // K tile, later overwritten by V tile
  __shared__ float Rk[128][PAD];
  __shared__ float P[64][PAD];
  __shared__ float rowm[64], rowl[64], rowscale[64];

  const int h = blockIdx.y;
  const int it = blockIdx.x;
  const int i0 = it * 64;
  const int tid = threadIdx.x;
  const int tx = tid & 15, ty = tid >> 4;

  // stage Qw = q + rwb, Qr = q + rrb   (64x64 each)
#pragma unroll
  for (int ch = 0; ch < 4; ++ch) {
    const int l4 = ch * 256 + tid;       // float4 index 0..1023
    const int row = l4 >> 4;             // 0..63
    const int col = (l4 & 15) << 2;      // 0..60
    const float4 qv = *(const float4*)(q + (i0 + row) * NH + h * DH + col);
    const float4 bw = *(const float4*)(rwb + h * DH + col);
    const float4 br = *(const float4*)(rrb + h * DH + col);
    float4 w, r2;
    w.x = qv.x + bw.x; w.y = qv.y + bw.y; w.z = qv.z + bw.z; w.w = qv.w + bw.w;
    r2.x = qv.x + br.x; r2.y = qv.y + br.y; r2.z = qv.z + br.z; r2.w = qv.w + br.w;
    *(float4*)&Qw[row][col] = w;
    *(float4*)&Qr[row][col] = r2;
  }
  if (tid < 64) {
    rowm[tid] = -1e30f;
    rowl[tid] = 0.0f;
  }

  float acc_o[4][4] = {};

  for (int jt = 0; jt <= it; ++jt) {
    const int j0 = jt * 64;
    const int Lo = S - 64 - i0 + j0;   // >= 0 always
    // stage K tile
#pragma unroll
    for (int ch = 0; ch < 4; ++ch) {
      const int l4 = ch * 256 + tid;
      const int row = l4 >> 4;
      const int col = (l4 & 15) << 2;
      *(float4*)&KV[row][col] =
          *(const float4*)(k + (j0 + row) * NH + h * DH + col);
    }
    // stage Rk window: rows Lo..Lo+127 (zero-fill past S; only masked j use them)
#pragma unroll
    for (int ch = 0; ch < 8; ++ch) {
      const int l4 = ch * 256 + tid;
      const int row = l4 >> 4;             // 0..127
      const int col = (l4 & 15) << 2;
      const int gr = Lo + row;
      float4 val = make_float4(0.f, 0.f, 0.f, 0.f);
      if (gr < S) val = *(const float4*)(rk + gr * NH + h * DH + col);
      *(float4*)&Rk[row][col] = val;
    }
    __syncthreads();

    // scores: thread covers rows ty*4..+3, cols tx*4..+3
    float sacc[4][4] = {};
    const int base = 63 - ty * 4 + tx * 4;  // Rk row for (r=0,c=0); row = base + c - r
#pragma unroll
    for (int d0 = 0; d0 < 64; d0 += 4) {
      float4 qw[4], qr[4], kv[4], rkv[7];
#pragma unroll
      for (int r = 0; r < 4; ++r) {
        qw[r] = *(const float4*)&Qw[ty * 4 + r][d0];
        qr[r] = *(const float4*)&Qr[ty * 4 + r][d0];
      }
#pragma unroll
      for (int c = 0; c < 4; ++c) kv[c] = *(const float4*)&KV[tx * 4 + c][d0];
#pragma unroll
      for (int m = 0; m < 7; ++m) rkv[m] = *(const float4*)&Rk[base + m - 3][d0];
#pragma unroll
      for (int r = 0; r < 4; ++r)
#pragma unroll
        for (int c = 0; c < 4; ++c) {
          const float4 rv = rkv[c - r + 3];
          sacc[r][c] += qw[r].x * kv[c].x + qw[r].y * kv[c].y +
                        qw[r].z * kv[c].z + qw[r].w * kv[c].w +
                        qr[r].x * rv.x + qr[r].y * rv.y +
                        qr[r].z * rv.z + qr[r].w * rv.w;
        }
    }
    // scale + causal mask + write P
    const bool diag = (jt == it);
#pragma unroll
    for (int r = 0; r < 4; ++r) {
      float4 p;
      float* pp = &p.x;
#pragma unroll
      for (int c = 0; c < 4; ++c) {
        float s = sacc[r][c] * 0.125f;
        if (diag && (tx * 4 + c) > (ty * 4 + r)) s = -1e30f;
        pp[c] = s;
      }
      *(float4*)&P[ty * 4 + r][tx * 4] = p;
    }
    __syncthreads();

    // softmax row update (threads 0..63) + stage V into KV (all threads)
    if (tid < 64) {
      const float mo = rowm[tid];
      float tmax = -1e30f;
#pragma unroll
      for (int j4 = 0; j4 < 16; ++j4) {
        const float4 p = *(const float4*)&P[tid][j4 * 4];
        tmax = fmaxf(tmax, fmaxf(fmaxf(p.x, p.y), fmaxf(p.z, p.w)));
      }
      const float nm = fmaxf(mo, tmax);
      const float corr = __expf(mo - nm);
      float sum = 0.f;
#pragma unroll
      for (int j4 = 0; j4 < 16; ++j4) {
        float4 p = *(const float4*)&P[tid][j4 * 4];
        p.x = __expf(p.x - nm);
        p.y = __expf(p.y - nm);
        p.z = __expf(p.z - nm);
        p.w = __expf(p.w - nm);
        *(float4*)&P[tid][j4 * 4] = p;
        sum += p.x + p.y + p.z + p.w;
      }
      rowl[tid] = rowl[tid] * corr + sum;
      rowm[tid] = nm;
      rowscale[tid] = corr;
    }
#pragma unroll
    for (int ch = 0; ch < 4; ++ch) {
      const int l4 = ch * 256 + tid;
      const int row = l4 >> 4;
      const int col = (l4 & 15) << 2;
      *(float4*)&KV[row][col] =
          *(const float4*)(v + (j0 + row) * NH + h * DH + col);
    }
    __syncthreads();

    // rescale accumulators and add P @ V
#pragma unroll
    for (int r = 0; r < 4; ++r) {
      const float corr = rowscale[ty * 4 + r];
#pragma unroll
      for (int c = 0; c < 4; ++c) acc_o[r][c] *= corr;
    }
#pragma unroll
    for (int jj = 0; jj < 64; jj += 4) {
      float4 pv[4], vv[4];
#pragma unroll
      for (int r = 0; r < 4; ++r) pv[r] = *(const float4*)&P[ty * 4 + r][jj];
#pragma unroll
      for (int s2 = 0; s2 < 4; ++s2)
        vv[s2] = *(const float4*)&KV[jj + s2][tx * 4];
#pragma unroll
      for (int r = 0; r < 4; ++r) {
        acc_o[r][0] += pv[r].x * vv[0].x + pv[r].y * vv[1].x +
                       pv[r].z * vv[2].x + pv[r].w * vv[3].x;
        acc_o[r][1] += pv[r].x * vv[0].y + pv[r].y * vv[1].y +
                       pv[r].z * vv[2].y + pv[r].w * vv[3].y;
        acc_o[r][2] += pv[r].x * vv[0].z + pv[r].y * vv[1].z +
                       pv[r].z * vv[2].z + pv[r].w * vv[3].z;
        acc_o[r][3] += pv[r].x * vv[0].w + pv[r].y * vv[1].w +
                       pv[r].z * vv[2].w + pv[r].w * vv[3].w;
      }
    }
    __syncthreads();  // before next iter overwrites KV/Rk/P
  }

  // epilogue: divide by l, write o[i][h][d]
#pragma unroll
  for (int r = 0; r < 4; ++r) {
    const int ii = ty * 4 + r;
    const float inv_l = 1.0f / rowl[ii];
    float4 out;
    out.x = acc_o[r][0] * inv_l;
    out.y = acc_o[r][1] * inv_l;
    out.z = acc_o[r][2] * inv_l;
    out.w = acc_o[r][3] * inv_l;
    *(float4*)(o + (i0 + ii) * NH + h * DH + tx * 4) = out;
  }
}

// ---------------------------------------------------------------------------
extern "C" void kernel_launch(void* const* d_in, const int* in_sizes, int n_in,
                              void* d_out, int out_size, void* d_ws,
                              size_t ws_size, hipStream_t stream) {
  const float* inq = (const float*)d_in[0];   // [1,S,F]
  const float* pos = (const float*)d_in[1];   // [S,F]
  const float* rwb = (const float*)d_in[2];   // [H,DH]
  const float* rrb = (const float*)d_in[3];   // [H,DH]
  const float* Wq  = (const float*)d_in[4];   // [F,H,DH]
  const float* bq  = (const float*)d_in[5];
  const float* Wk  = (const float*)d_in[6];
  const float* bk  = (const float*)d_in[7];
  const float* Wv  = (const float*)d_in[8];
  const float* bv  = (const float*)d_in[9];
  const float* Wr  = (const float*)d_in[10];
  const float* br  = (const float*)d_in[11];
  const float* Wo  = (const float*)d_in[12];  // [H,DH,F]
  const float* bo  = (const float*)d_in[13];  // [F]

  float* ws = (float*)d_ws;
  float* qb = ws;                      // [S][NH]
  float* kb = ws + 2 * 1024 * 1024;
  float* vb = ws + 4 * 1024 * 1024;
  float* rb = ws + 6 * 1024 * 1024;
  float* ab = ws + 8 * 1024 * 1024;    // attention output [S][NH]

  const dim3 gproj(NH / 64, S / 64);   // (16, 32)
  gemm_bias<<<gproj, 256, 0, stream>>>(inq, Wq, bq, qb, S, NH, F);
  gemm_bias<<<gproj, 256, 0, stream>>>(inq, Wk, bk, kb, S, NH, F);
  gemm_bias<<<gproj, 256, 0, stream>>>(inq, Wv, bv, vb, S, NH, F);
  gemm_bias<<<gproj, 256, 0, stream>>>(pos, Wr, br, rb, S, NH, F);

  attn_kernel<<<dim3(S / 64, H), 256, 0, stream>>>(qb, kb, vb, rb, rwb, rrb, ab);

  gemm_bias<<<dim3(F / 64, S / 64), 256, 0, stream>>>(ab, Wo, bo, (float*)d_out,
                                                      S, F, NH);
}

// Round 3
// 262.228 us; speedup vs baseline: 6.4536x; 6.4536x over previous
//
#include <hip/hip_runtime.h>

#define S 2048
#define F 1024
#define H 16
#define DH 64
#define NH (H * DH)   // 1024

typedef __attribute__((ext_vector_type(8))) short bf16x8;
typedef __attribute__((ext_vector_type(4))) float f32x4;

__device__ __forceinline__ ushort f2bf(float f) {
  unsigned u = __float_as_uint(f);
  u = (u + 0x7FFFu + ((u >> 16) & 1u)) >> 16;
  return (ushort)u;
}
__device__ __forceinline__ float bf2f(ushort u) {
  return __uint_as_float(((unsigned)u) << 16);
}

// async global->LDS, 16B per lane. LDS dest must be linear (wave-uniform base +
// lane*16); swizzle achieved by pre-swizzling the GLOBAL source address.
__device__ __forceinline__ void gload16(const void* g, void* l) {
  __builtin_amdgcn_global_load_lds(
      (const __attribute__((address_space(1))) void*)g,
      (__attribute__((address_space(3))) void*)l, 16, 0, 0);
}

// swizzled bf16x8 fragment read from a [rows][128B] LDS tile.
// byte ^= ((row&7)<<4) spreads the 16 rows of an MFMA fragment across banks.
__device__ __forceinline__ bf16x8 ldsT(const ushort* buf, int row, int kbyte) {
  return *(const bf16x8*)((const char*)buf + row * 128 +
                          (kbyte ^ ((row & 7) << 4)));
}

// ---------------------------------------------------------------------------
// fp32 -> bf16 elementwise convert
// ---------------------------------------------------------------------------
__global__ __launch_bounds__(256) void conv_bf16(const float* __restrict__ src,
                                                 ushort* __restrict__ dst,
                                                 int n) {
  const int i = (blockIdx.x * 256 + threadIdx.x) * 4;
  if (i < n) {
    const float4 v = *(const float4*)(src + i);
    ushort4 u;
    u.x = f2bf(v.x); u.y = f2bf(v.y); u.z = f2bf(v.z); u.w = f2bf(v.w);
    *(ushort4*)(dst + i) = u;
  }
}

// ---------------------------------------------------------------------------
// 1024x1024 fp32 [K][N] -> bf16 [N][K] transpose-convert (for GEMM B operands)
// ---------------------------------------------------------------------------
__global__ __launch_bounds__(256) void tconv(const float* __restrict__ src,
                                             ushort* __restrict__ dst) {
  __shared__ ushort T[64][72];
  const int r0 = blockIdx.y * 64, c0 = blockIdx.x * 64;
  const int t = threadIdx.x;
#pragma unroll
  for (int q = 0; q < 4; ++q) {
    const int row = q * 16 + (t >> 4);
    const int col = (t & 15) * 4;
    const float4 v = *(const float4*)(src + (size_t)(r0 + row) * 1024 + c0 + col);
    T[row][col + 0] = f2bf(v.x);
    T[row][col + 1] = f2bf(v.y);
    T[row][col + 2] = f2bf(v.z);
    T[row][col + 3] = f2bf(v.w);
  }
  __syncthreads();
#pragma unroll
  for (int q = 0; q < 4; ++q) {
    const int orow = q * 16 + (t >> 4);   // output row = src col
    const int ocol = (t & 15) * 4;        // output col = src row
    ushort4 u;
    u.x = T[ocol + 0][orow];
    u.y = T[ocol + 1][orow];
    u.z = T[ocol + 2][orow];
    u.w = T[ocol + 3][orow];
    *(ushort4*)(dst + (size_t)(c0 + orow) * 1024 + r0 + ocol) = u;
  }
}

// ---------------------------------------------------------------------------
// bf16 MFMA GEMM: C[M][N] = A[M][K] * Bt[N][K]^T + bias
// tile 64x128, BK=64, 4 waves (2x2), wave = 32x64, dbuf global_load_lds.
// EPI: 0 = bf16 C+bias; 1 = two bf16 outs (+bias+bw / +bias+br2) [Q];
//      2 = bf16 transposed C[N][M] (+bias) [V]; 3 = fp32 C+bias [final]
// ---------------------------------------------------------------------------
template <int EPI>
__global__ __launch_bounds__(256, 2) void mm_bf16(
    const ushort* __restrict__ A, const ushort* __restrict__ Bt,
    const float* __restrict__ bias, const float* __restrict__ bw,
    const float* __restrict__ br2, void* __restrict__ Cout,
    void* __restrict__ C2, int M, int N, int K) {
  __shared__ __align__(16) ushort Asb[2][64 * 64];
  __shared__ __align__(16) ushort Bsb[2][128 * 64];
  const int tid = threadIdx.x;
  const int l = tid & 63, w = tid >> 6;
  const int wm = w >> 1, wn = w & 1;
  const int m0 = blockIdx.y * 64, n0 = blockIdx.x * 128;

  f32x4 acc[2][4];
#pragma unroll
  for (int m = 0; m < 2; ++m)
#pragma unroll
    for (int n = 0; n < 4; ++n) acc[m][n] = (f32x4){0.f, 0.f, 0.f, 0.f};

#define MM_STAGE(c, kt)                                                        \
  {                                                                            \
    const int k0 = (kt) * 64;                                                  \
    _Pragma("unroll") for (int i = 0; i < 2; ++i) {                            \
      const int LB = (i * 256 + tid) * 16, row = LB >> 7, rb_ = LB & 127;      \
      const int tb = rb_ ^ ((row & 7) << 4);                                   \
      gload16((const char*)A + ((size_t)(m0 + row) * K + k0) * 2 + tb,         \
              (char*)Asb[c] + LB);                                             \
    }                                                                          \
    _Pragma("unroll") for (int i = 0; i < 4; ++i) {                            \
      const int LB = (i * 256 + tid) * 16, row = LB >> 7, rb_ = LB & 127;      \
      const int tb = rb_ ^ ((row & 7) << 4);                                   \
      gload16((const char*)Bt + ((size_t)(n0 + row) * K + k0) * 2 + tb,        \
              (char*)Bsb[c] + LB);                                             \
    }                                                                          \
  }

  MM_STAGE(0, 0);
  __syncthreads();
  const int NT = K >> 6;
  int cur = 0;
  for (int kt = 0; kt < NT; ++kt) {
    if (kt + 1 < NT) MM_STAGE(cur ^ 1, kt + 1);
#pragma unroll
    for (int ks = 0; ks < 2; ++ks) {
      bf16x8 af[2], bfr[4];
#pragma unroll
      for (int m = 0; m < 2; ++m)
        af[m] = ldsT(Asb[cur], wm * 32 + m * 16 + (l & 15),
                     ks * 64 + (l >> 4) * 16);
#pragma unroll
      for (int n = 0; n < 4; ++n)
        bfr[n] = ldsT(Bsb[cur], wn * 64 + n * 16 + (l & 15),
                      ks * 64 + (l >> 4) * 16);
#pragma unroll
      for (int m = 0; m < 2; ++m)
#pragma unroll
        for (int n = 0; n < 4; ++n)
          acc[m][n] = __builtin_amdgcn_mfma_f32_16x16x32_bf16(
              af[m], bfr[n], acc[m][n], 0, 0, 0);
    }
    __syncthreads();
    cur ^= 1;
  }

#pragma unroll
  for (int m = 0; m < 2; ++m)
#pragma unroll
    for (int n = 0; n < 4; ++n) {
      const int colg = n0 + wn * 64 + n * 16 + (l & 15);
      const int rowb = m0 + wm * 32 + m * 16 + (l >> 4) * 4;
      const float bs = bias[colg];
      if constexpr (EPI == 0) {
        ushort* C = (ushort*)Cout;
#pragma unroll
        for (int r = 0; r < 4; ++r)
          C[(size_t)(rowb + r) * N + colg] = f2bf(acc[m][n][r] + bs);
      } else if constexpr (EPI == 1) {
        ushort* Cw = (ushort*)Cout;
        ushort* Cr = (ushort*)C2;
        const float b2 = bw[colg], b3 = br2[colg];
#pragma unroll
        for (int r = 0; r < 4; ++r) {
          const float v = acc[m][n][r] + bs;
          Cw[(size_t)(rowb + r) * N + colg] = f2bf(v + b2);
          Cr[(size_t)(rowb + r) * N + colg] = f2bf(v + b3);
        }
      } else if constexpr (EPI == 2) {
        ushort* C = (ushort*)Cout;  // [N][M] transposed
        ushort4 u;
        u.x = f2bf(acc[m][n][0] + bs);
        u.y = f2bf(acc[m][n][1] + bs);
        u.z = f2bf(acc[m][n][2] + bs);
        u.w = f2bf(acc[m][n][3] + bs);
        *(ushort4*)(C + (size_t)colg * M + rowb) = u;
      } else {
        float* C = (float*)Cout;
#pragma unroll
        for (int r = 0; r < 4; ++r)
          C[(size_t)(rowb + r) * N + colg] = acc[m][n][r] + bs;
      }
    }
}

// ---------------------------------------------------------------------------
// Fused rel-attention, bf16 MFMA. Block = (64-q-tile, head), 4 waves, each
// wave owns 16 q-rows. j-tiles descend it..0; per step one new BDlag t-tile.
//   score[i,j] = ( qw[i]·k[j] + qr[i]·rkey[S-1-(i-j)] ) / 8, j<=i
//   BDlag[i][64*tp+tt] = qr[i]·rkey[S-1-64*tp-tt];  BD[i][j]=BDlag[i][i-j]
// ---------------------------------------------------------------------------
__global__ __launch_bounds__(256, 2) void attn_mfma(
    const ushort* __restrict__ qw, const ushort* __restrict__ qr,
    const ushort* __restrict__ kb, const ushort* __restrict__ vt,
    const ushort* __restrict__ rb, ushort* __restrict__ ab) {
  __shared__ __align__(16) ushort Kb[2][64 * 64];
  __shared__ __align__(16) ushort Vb[2][64 * 64];
  __shared__ __align__(16) ushort Rb[2][64 * 64];
  __shared__ __align__(16) ushort BDb[2][64 * 64];
  __shared__ __align__(16) ushort Pb[4][16 * 64];

  const int bx = blockIdx.x;
  const int it = 31 - (bx >> 4);  // big tiles dispatched first (load balance)
  const int h = bx & 15;
  const int i0 = it * 64;
  const int tid = threadIdx.x;
  const int l = tid & 63, w = tid >> 6;

  // ---- stage Q tiles (linear, unswizzled; read once) into Kb[0]/Kb[1]
#pragma unroll
  for (int i = 0; i < 2; ++i) {
    const int LB = (i * 256 + tid) * 16, row = LB >> 7, rb_ = LB & 127;
    gload16((const char*)qw + ((size_t)(i0 + row) * NH + h * 64) * 2 + rb_,
            (char*)Kb[0] + LB);
    gload16((const char*)qr + ((size_t)(i0 + row) * NH + h * 64) * 2 + rb_,
            (char*)Kb[1] + LB);
  }
  __syncthreads();
  bf16x8 qwf[2], qrf[2];
#pragma unroll
  for (int ks = 0; ks < 2; ++ks) {
    const int row = w * 16 + (l & 15);
    const int kbyte = ks * 64 + (l >> 4) * 16;
    qwf[ks] = *(const bf16x8*)((const char*)Kb[0] + row * 128 + kbyte);
    qrf[ks] = *(const bf16x8*)((const char*)Kb[1] + row * 128 + kbyte);
  }
  __syncthreads();

  f32x4 acc_o[4];
#pragma unroll
  for (int n = 0; n < 4; ++n) acc_o[n] = (f32x4){0.f, 0.f, 0.f, 0.f};
  float m_r[4] = {-1e30f, -1e30f, -1e30f, -1e30f};
  float l_r[4] = {0.f, 0.f, 0.f, 0.f};

  // K tile: [j][d]; Vt tile: [d][j]; R tile: [tt][d] (rows reversed in global)
#define AT_STAGE(c, jt_)                                                       \
  {                                                                            \
    const int j0 = (jt_) * 64;                                                 \
    const int tp_ = it - (jt_);                                                \
    _Pragma("unroll") for (int i = 0; i < 2; ++i) {                            \
      const int LB = (i * 256 + tid) * 16, row = LB >> 7, rb_ = LB & 127;      \
      const int tb = rb_ ^ ((row & 7) << 4);                                   \
      gload16((const char*)kb + ((size_t)(j0 + row) * NH + h * 64) * 2 + tb,   \
              (char*)Kb[c] + LB);                                              \
      gload16((const char*)vt + ((size_t)(h * 64 + row) * S + j0) * 2 + tb,    \
              (char*)Vb[c] + LB);                                              \
      gload16((const char*)rb +                                                \
                  ((size_t)(S - 1 - 64 * tp_ - row) * NH + h * 64) * 2 + tb,   \
              (char*)Rb[c] + LB);                                              \
    }                                                                          \
  }

  AT_STAGE(0, it);
  __syncthreads();
  int cur = 0;
  for (int jt = it; jt >= 0; --jt) {
    const int tp = it - jt;
    if (jt > 0) AT_STAGE(cur ^ 1, jt - 1);  // prefetch in flight over compute

    // --- BDlag tile: bd = Qr(16x64) x Rb(64x64)^T
    f32x4 bd[4];
#pragma unroll
    for (int n = 0; n < 4; ++n) bd[n] = (f32x4){0.f, 0.f, 0.f, 0.f};
#pragma unroll
    for (int ks = 0; ks < 2; ++ks) {
      bf16x8 rf[4];
#pragma unroll
      for (int n = 0; n < 4; ++n)
        rf[n] = ldsT(Rb[cur], n * 16 + (l & 15), ks * 64 + (l >> 4) * 16);
#pragma unroll
      for (int n = 0; n < 4; ++n)
        bd[n] = __builtin_amdgcn_mfma_f32_16x16x32_bf16(qrf[ks], rf[n], bd[n],
                                                        0, 0, 0);
    }
    {
      ushort* B = BDb[tp & 1];
#pragma unroll
      for (int n = 0; n < 4; ++n)
#pragma unroll
        for (int r = 0; r < 4; ++r) {
          const int row = w * 16 + (l >> 4) * 4 + r;
          B[row * 64 + n * 16 + (l & 15)] = f2bf(bd[n][r]);
        }
    }

    // --- AC tile: sa = Qw(16x64) x Kb(64x64)^T
    f32x4 sa[4];
#pragma unroll
    for (int n = 0; n < 4; ++n) sa[n] = (f32x4){0.f, 0.f, 0.f, 0.f};
#pragma unroll
    for (int ks = 0; ks < 2; ++ks) {
      bf16x8 kf[4];
#pragma unroll
      for (int n = 0; n < 4; ++n)
        kf[n] = ldsT(Kb[cur], n * 16 + (l & 15), ks * 64 + (l >> 4) * 16);
#pragma unroll
      for (int n = 0; n < 4; ++n)
        sa[n] = __builtin_amdgcn_mfma_f32_16x16x32_bf16(qwf[ks], kf[n], sa[n],
                                                        0, 0, 0);
    }

    // --- shear BD + mask + online softmax (wave-local; rows in-register)
    const ushort* Bnew = BDb[tp & 1];
    const ushort* Bold = BDb[(tp & 1) ^ 1];
    float p[4][4];
    float rmax[4] = {-1e30f, -1e30f, -1e30f, -1e30f};
#pragma unroll
    for (int n = 0; n < 4; ++n)
#pragma unroll
      for (int r = 0; r < 4; ++r) {
        const int fr = w * 16 + (l >> 4) * 4 + r;  // row in 64-q-tile
        const int jj = n * 16 + (l & 15);
        const int u = 64 + fr - jj;  // in [1,127]
        const float bdv =
            bf2f((u >= 64) ? Bnew[fr * 64 + (u - 64)] : Bold[fr * 64 + u]);
        float s = (sa[n][r] + bdv) * 0.125f;
        if (tp == 0 && jj > fr) s = -1e30f;  // causal mask (diag tile only)
        p[n][r] = s;
        rmax[r] = fmaxf(rmax[r], s);
      }
#pragma unroll
    for (int off = 1; off < 16; off <<= 1)
#pragma unroll
      for (int r = 0; r < 4; ++r)
        rmax[r] = fmaxf(rmax[r], __shfl_xor(rmax[r], off, 64));
    float corr[4];
#pragma unroll
    for (int r = 0; r < 4; ++r) {
      const float mn = fmaxf(m_r[r], rmax[r]);
      corr[r] = __expf(m_r[r] - mn);
      m_r[r] = mn;
    }
    float rsum[4] = {0.f, 0.f, 0.f, 0.f};
#pragma unroll
    for (int n = 0; n < 4; ++n)
#pragma unroll
      for (int r = 0; r < 4; ++r) {
        p[n][r] = __expf(p[n][r] - m_r[r]);
        rsum[r] += p[n][r];
      }
#pragma unroll
    for (int off = 1; off < 16; off <<= 1)
#pragma unroll
      for (int r = 0; r < 4; ++r) rsum[r] += __shfl_xor(rsum[r], off, 64);
#pragma unroll
    for (int r = 0; r < 4; ++r) l_r[r] = l_r[r] * corr[r] + rsum[r];
#pragma unroll
    for (int n = 0; n < 4; ++n)
#pragma unroll
      for (int r = 0; r < 4; ++r) acc_o[n][r] *= corr[r];

    // --- write P (swizzled), wave-private buffer
    {
      ushort* P = Pb[w];
#pragma unroll
      for (int n = 0; n < 4; ++n)
#pragma unroll
        for (int r = 0; r < 4; ++r) {
          const int row = (l >> 4) * 4 + r;
          const int colb = (n * 16 + (l & 15)) * 2;
          *(ushort*)((char*)P + row * 128 + (colb ^ ((row & 7) << 4))) =
              f2bf(p[n][r]);
        }
    }

    // --- PV: acc_o += P(16x64) x Vt
#pragma unroll
    for (int ks = 0; ks < 2; ++ks) {
      const int prow = l & 15;
      const bf16x8 pf = *(const bf16x8*)(
          (const char*)Pb[w] + prow * 128 +
          ((ks * 64 + (l >> 4) * 16) ^ ((prow & 7) << 4)));
      bf16x8 vf[4];
#pragma unroll
      for (int n = 0; n < 4; ++n)
        vf[n] = ldsT(Vb[cur], n * 16 + (l & 15), ks * 64 + (l >> 4) * 16);
#pragma unroll
      for (int n = 0; n < 4; ++n)
        acc_o[n] = __builtin_amdgcn_mfma_f32_16x16x32_bf16(pf, vf[n], acc_o[n],
                                                           0, 0, 0);
    }
    __syncthreads();
    cur ^= 1;
  }

  // --- epilogue
  float inv[4];
#pragma unroll
  for (int r = 0; r < 4; ++r) inv[r] = 1.f / l_r[r];
#pragma unroll
  for (int n = 0; n < 4; ++n)
#pragma unroll
    for (int r = 0; r < 4; ++r) {
      const int row = i0 + w * 16 + (l >> 4) * 4 + r;
      const int col = h * 64 + n * 16 + (l & 15);
      ab[(size_t)row * NH + col] = f2bf(acc_o[n][r] * inv[r]);
    }
}

// ---------------------------------------------------------------------------
extern "C" void kernel_launch(void* const* d_in, const int* in_sizes, int n_in,
                              void* d_out, int out_size, void* d_ws,
                              size_t ws_size, hipStream_t stream) {
  const float* inq = (const float*)d_in[0];
  const float* pos = (const float*)d_in[1];
  const float* rwb = (const float*)d_in[2];
  const float* rrb = (const float*)d_in[3];
  const float* Wq = (const float*)d_in[4];
  const float* bq = (const float*)d_in[5];
  const float* Wk = (const float*)d_in[6];
  const float* bk = (const float*)d_in[7];
  const float* Wv = (const float*)d_in[8];
  const float* bv = (const float*)d_in[9];
  const float* Wr = (const float*)d_in[10];
  const float* br = (const float*)d_in[11];
  const float* Wo = (const float*)d_in[12];
  const float* bo = (const float*)d_in[13];

  char* ws = (char*)d_ws;
  const size_t MB = 1024 * 1024;
  ushort* A_bf = (ushort*)(ws + 0 * MB);    // inq bf16 [S][F]   (aliased by ab)
  ushort* P_bf = (ushort*)(ws + 4 * MB);    // pos bf16 [S][F]
  ushort* Wqt = (ushort*)(ws + 8 * MB);     // [NH][F]
  ushort* Wkt = (ushort*)(ws + 10 * MB);
  ushort* Wvt = (ushort*)(ws + 12 * MB);
  ushort* Wrt = (ushort*)(ws + 14 * MB);
  ushort* Wot = (ushort*)(ws + 16 * MB);    // [F][NH]
  ushort* qwp = (ushort*)(ws + 18 * MB);    // [S][NH]
  ushort* qrp = (ushort*)(ws + 22 * MB);
  ushort* kbp = (ushort*)(ws + 26 * MB);
  ushort* vtp = (ushort*)(ws + 30 * MB);    // [NH][S]
  ushort* rbp = (ushort*)(ws + 34 * MB);
  ushort* abp = A_bf;  // alias: A_bf dead after V-GEMM, attn writes ab here

  conv_bf16<<<2048, 256, 0, stream>>>(inq, A_bf, S * F);
  conv_bf16<<<2048, 256, 0, stream>>>(pos, P_bf, S * F);
  const dim3 gt(16, 16);
  tconv<<<gt, 256, 0, stream>>>(Wq, Wqt);
  tconv<<<gt, 256, 0, stream>>>(Wk, Wkt);
  tconv<<<gt, 256, 0, stream>>>(Wv, Wvt);
  tconv<<<gt, 256, 0, stream>>>(Wr, Wrt);
  tconv<<<gt, 256, 0, stream>>>(Wo, Wot);

  const dim3 gg(NH / 128, S / 64);  // (8, 32)
  mm_bf16<1><<<gg, 256, 0, stream>>>(A_bf, Wqt, bq, rwb, rrb, qwp, qrp,
                                     S, NH, F);
  mm_bf16<0><<<gg, 256, 0, stream>>>(A_bf, Wkt, bk, nullptr, nullptr, kbp,
                                     nullptr, S, NH, F);
  mm_bf16<2><<<gg, 256, 0, stream>>>(A_bf, Wvt, bv, nullptr, nullptr, vtp,
                                     nullptr, S, NH, F);
  mm_bf16<0><<<gg, 256, 0, stream>>>(P_bf, Wrt, br, nullptr, nullptr, rbp,
                                     nullptr, S, NH, F);

  attn_mfma<<<512, 256, 0, stream>>>(qwp, qrp, kbp, vtp, rbp, abp);

  mm_bf16<3><<<dim3(F / 128, S / 64), 256, 0, stream>>>(
      abp, Wot, bo, nullptr, nullptr, d_out, nullptr, S, F, NH);
}

// Round 4
// 214.714 us; speedup vs baseline: 7.8817x; 1.2213x over previous
//
#include <hip/hip_runtime.h>

#define S 2048
#define F 1024
#define H 16
#define DH 64
#define NH (H * DH)   // 1024

typedef __attribute__((ext_vector_type(8))) short bf16x8;
typedef __attribute__((ext_vector_type(4))) float f32x4;

__device__ __forceinline__ ushort f2bf(float f) {
  unsigned u = __float_as_uint(f);
  u = (u + 0x7FFFu + ((u >> 16) & 1u)) >> 16;
  return (ushort)u;
}
__device__ __forceinline__ float bf2f(ushort u) {
  return __uint_as_float(((unsigned)u) << 16);
}

__device__ __forceinline__ void gload16(const void* g, void* l) {
  __builtin_amdgcn_global_load_lds(
      (const __attribute__((address_space(1))) void*)g,
      (__attribute__((address_space(3))) void*)l, 16, 0, 0);
}

// swizzled bf16x8 fragment read from a [rows][128B] LDS tile.
__device__ __forceinline__ bf16x8 ldsT(const ushort* buf, int row, int kbyte) {
  return *(const bf16x8*)((const char*)buf + row * 128 +
                          (kbyte ^ ((row & 7) << 4)));
}

// ---------------------------------------------------------------------------
__global__ __launch_bounds__(256) void conv_bf16(const float* __restrict__ src,
                                                 ushort* __restrict__ dst,
                                                 int n) {
  const int i = (blockIdx.x * 256 + threadIdx.x) * 4;
  if (i < n) {
    const float4 v = *(const float4*)(src + i);
    ushort4 u;
    u.x = f2bf(v.x); u.y = f2bf(v.y); u.z = f2bf(v.z); u.w = f2bf(v.w);
    *(ushort4*)(dst + i) = u;
  }
}

// ---------------------------------------------------------------------------
__global__ __launch_bounds__(256) void tconv(const float* __restrict__ src,
                                             ushort* __restrict__ dst) {
  __shared__ ushort T[64][72];
  const int r0 = blockIdx.y * 64, c0 = blockIdx.x * 64;
  const int t = threadIdx.x;
#pragma unroll
  for (int q = 0; q < 4; ++q) {
    const int row = q * 16 + (t >> 4);
    const int col = (t & 15) * 4;
    const float4 v = *(const float4*)(src + (size_t)(r0 + row) * 1024 + c0 + col);
    T[row][col + 0] = f2bf(v.x);
    T[row][col + 1] = f2bf(v.y);
    T[row][col + 2] = f2bf(v.z);
    T[row][col + 3] = f2bf(v.w);
  }
  __syncthreads();
#pragma unroll
  for (int q = 0; q < 4; ++q) {
    const int orow = q * 16 + (t >> 4);
    const int ocol = (t & 15) * 4;
    ushort4 u;
    u.x = T[ocol + 0][orow];
    u.y = T[ocol + 1][orow];
    u.z = T[ocol + 2][orow];
    u.w = T[ocol + 3][orow];
    *(ushort4*)(dst + (size_t)(c0 + orow) * 1024 + r0 + ocol) = u;
  }
}

// ---------------------------------------------------------------------------
// bf16 MFMA GEMM, tile 64x128, BK=64, 4 waves, dbuf global_load_lds.
// EPI 0: bf16 out + bias[b0] -> o0
// EPI 3: fp32 out + bias[b0] -> o0
// EPI 4: fused QKV (N=3072): band0 Q -> o0(+b0+b1)/o1(+b0+b2);
//        band1 K -> o2(+b3); band2 V -> o3 transposed [NH][S] (+b4)
// ---------------------------------------------------------------------------
template <int EPI>
__global__ __launch_bounds__(256, 2) void mm_bf16(
    const ushort* __restrict__ A, const ushort* __restrict__ Bt,
    const float* __restrict__ b0, const float* __restrict__ b1,
    const float* __restrict__ b2, const float* __restrict__ b3,
    const float* __restrict__ b4, void* __restrict__ o0, void* __restrict__ o1,
    void* __restrict__ o2, void* __restrict__ o3, int M, int N, int K) {
  __shared__ __align__(16) ushort Asb[2][64 * 64];
  __shared__ __align__(16) ushort Bsb[2][128 * 64];
  const int tid = threadIdx.x;
  const int l = tid & 63, w = tid >> 6;
  const int wm = w >> 1, wn = w & 1;
  const int m0 = blockIdx.y * 64, n0 = blockIdx.x * 128;

  f32x4 acc[2][4];
#pragma unroll
  for (int m = 0; m < 2; ++m)
#pragma unroll
    for (int n = 0; n < 4; ++n) acc[m][n] = (f32x4){0.f, 0.f, 0.f, 0.f};

#define MM_STAGE(c, kt)                                                        \
  {                                                                            \
    const int k0 = (kt) * 64;                                                  \
    _Pragma("unroll") for (int i = 0; i < 2; ++i) {                            \
      const int LB = (i * 256 + tid) * 16, row = LB >> 7, rb_ = LB & 127;      \
      const int tb = rb_ ^ ((row & 7) << 4);                                   \
      gload16((const char*)A + ((size_t)(m0 + row) * K + k0) * 2 + tb,         \
              (char*)Asb[c] + LB);                                             \
    }                                                                          \
    _Pragma("unroll") for (int i = 0; i < 4; ++i) {                            \
      const int LB = (i * 256 + tid) * 16, row = LB >> 7, rb_ = LB & 127;      \
      const int tb = rb_ ^ ((row & 7) << 4);                                   \
      gload16((const char*)Bt + ((size_t)(n0 + row) * K + k0) * 2 + tb,        \
              (char*)Bsb[c] + LB);                                             \
    }                                                                          \
  }

  MM_STAGE(0, 0);
  __syncthreads();
  const int NT = K >> 6;
  int cur = 0;
  for (int kt = 0; kt < NT; ++kt) {
    if (kt + 1 < NT) MM_STAGE(cur ^ 1, kt + 1);
#pragma unroll
    for (int ks = 0; ks < 2; ++ks) {
      bf16x8 af[2], bfr[4];
#pragma unroll
      for (int m = 0; m < 2; ++m)
        af[m] = ldsT(Asb[cur], wm * 32 + m * 16 + (l & 15),
                     ks * 64 + (l >> 4) * 16);
#pragma unroll
      for (int n = 0; n < 4; ++n)
        bfr[n] = ldsT(Bsb[cur], wn * 64 + n * 16 + (l & 15),
                      ks * 64 + (l >> 4) * 16);
      __builtin_amdgcn_s_setprio(1);
#pragma unroll
      for (int m = 0; m < 2; ++m)
#pragma unroll
        for (int n = 0; n < 4; ++n)
          acc[m][n] = __builtin_amdgcn_mfma_f32_16x16x32_bf16(
              af[m], bfr[n], acc[m][n], 0, 0, 0);
      __builtin_amdgcn_s_setprio(0);
    }
    __syncthreads();
    cur ^= 1;
  }

#pragma unroll
  for (int m = 0; m < 2; ++m)
#pragma unroll
    for (int n = 0; n < 4; ++n) {
      const int colg = n0 + wn * 64 + n * 16 + (l & 15);
      const int rowb = m0 + wm * 32 + m * 16 + (l >> 4) * 4;
      if constexpr (EPI == 0) {
        ushort* C = (ushort*)o0;
        const float bs = b0[colg];
#pragma unroll
        for (int r = 0; r < 4; ++r)
          C[(size_t)(rowb + r) * N + colg] = f2bf(acc[m][n][r] + bs);
      } else if constexpr (EPI == 3) {
        float* C = (float*)o0;
        const float bs = b0[colg];
#pragma unroll
        for (int r = 0; r < 4; ++r)
          C[(size_t)(rowb + r) * N + colg] = acc[m][n][r] + bs;
      } else {  // EPI == 4, fused QKV, N = 3072
        const int band = colg >> 10;
        const int colm = colg & 1023;
        if (band == 0) {
          const float bs = b0[colm], vw = b1[colm], vr = b2[colm];
          ushort* Cw = (ushort*)o0;
          ushort* Cr = (ushort*)o1;
#pragma unroll
          for (int r = 0; r < 4; ++r) {
            const float v = acc[m][n][r] + bs;
            Cw[(size_t)(rowb + r) * NH + colm] = f2bf(v + vw);
            Cr[(size_t)(rowb + r) * NH + colm] = f2bf(v + vr);
          }
        } else if (band == 1) {
          const float bs = b3[colm];
          ushort* C = (ushort*)o2;
#pragma unroll
          for (int r = 0; r < 4; ++r)
            C[(size_t)(rowb + r) * NH + colm] = f2bf(acc[m][n][r] + bs);
        } else {
          const float bs = b4[colm];
          ushort* C = (ushort*)o3;  // [NH][S] transposed
          ushort4 u;
          u.x = f2bf(acc[m][n][0] + bs);
          u.y = f2bf(acc[m][n][1] + bs);
          u.z = f2bf(acc[m][n][2] + bs);
          u.w = f2bf(acc[m][n][3] + bs);
          *(ushort4*)(C + (size_t)colm * M + rowb) = u;
        }
      }
    }
}

// ---------------------------------------------------------------------------
// Fused rel-attention, split-j halves with unnormalized partials.
// Block = (i-tile, half, head); 4 waves x 16 q-rows. halfA: jt in [lo, it]
// (includes diagonal); halfB: jt in [0, lo). Partials: m, l, accU (f32).
// l computed via ones-column MFMA (no per-step sum shuffle reduce).
// ---------------------------------------------------------------------------
__global__ __launch_bounds__(256, 2) void attn_mfma(
    const ushort* __restrict__ qw, const ushort* __restrict__ qr,
    const ushort* __restrict__ kb, const ushort* __restrict__ vt,
    const ushort* __restrict__ rb, float* __restrict__ accA,
    float* __restrict__ accB, float* __restrict__ mA, float* __restrict__ lA,
    float* __restrict__ mB, float* __restrict__ lB) {
  __shared__ __align__(16) ushort Kb[2][64 * 64];
  __shared__ __align__(16) ushort Vb[2][64 * 64];
  __shared__ __align__(16) ushort Rb[2][64 * 64];
  __shared__ __align__(16) ushort BDb[2][64 * 64];
  __shared__ __align__(16) ushort Pb[4][16 * 64];

  const int bx = blockIdx.x;
  const int it = 31 - (bx >> 5);  // biggest i-tiles dispatched first (LPT)
  const int half = (bx >> 4) & 1;
  const int h = bx & 15;
  const int i0 = it * 64;
  const int tid = threadIdx.x;
  const int l = tid & 63, w = tid >> 6;
  const int lo = (it + 1) >> 1;
  const int fr_base = w * 16 + (l >> 4) * 4;

  float* __restrict__ accX = half ? accB : accA;
  float* __restrict__ mX = half ? mB : mA;
  float* __restrict__ lX = half ? lB : lA;

  if (half == 1 && lo == 0) {  // it==0 halfB: empty -> neutral partials
#pragma unroll
    for (int n = 0; n < 4; ++n)
#pragma unroll
      for (int r = 0; r < 4; ++r)
        accX[(size_t)(i0 + fr_base + r) * NH + h * 64 + n * 16 + (l & 15)] =
            0.f;
    if ((l & 15) == 0)
#pragma unroll
      for (int r = 0; r < 4; ++r) {
        mX[(i0 + fr_base + r) * H + h] = -1e30f;
        lX[(i0 + fr_base + r) * H + h] = 0.f;
      }
    return;
  }

  const int jstart = half ? (lo - 1) : it;
  const int jend = half ? 0 : lo;
  const int tp0 = it - jstart;

  // ---- stage Q tiles into Kb[0]/Kb[1] (linear), pull frags to registers
#pragma unroll
  for (int i = 0; i < 2; ++i) {
    const int LB = (i * 256 + tid) * 16, row = LB >> 7, rb_ = LB & 127;
    gload16((const char*)qw + ((size_t)(i0 + row) * NH + h * 64) * 2 + rb_,
            (char*)Kb[0] + LB);
    gload16((const char*)qr + ((size_t)(i0 + row) * NH + h * 64) * 2 + rb_,
            (char*)Kb[1] + LB);
  }
  __syncthreads();
  bf16x8 qwf[2], qrf[2];
#pragma unroll
  for (int ks = 0; ks < 2; ++ks) {
    const int row = w * 16 + (l & 15);
    const int kbyte = ks * 64 + (l >> 4) * 16;
    qwf[ks] = *(const bf16x8*)((const char*)Kb[0] + row * 128 + kbyte);
    qrf[ks] = *(const bf16x8*)((const char*)Kb[1] + row * 128 + kbyte);
  }
  __syncthreads();

  f32x4 acc_o[4];
#pragma unroll
  for (int n = 0; n < 4; ++n) acc_o[n] = (f32x4){0.f, 0.f, 0.f, 0.f};
  f32x4 acc_l = (f32x4){0.f, 0.f, 0.f, 0.f};
  float m_r[4] = {-1e30f, -1e30f, -1e30f, -1e30f};

  const short one_bf = (short)0x3F80;
  const bf16x8 ones = {one_bf, one_bf, one_bf, one_bf,
                       one_bf, one_bf, one_bf, one_bf};

#define AT_STAGE(c, jt_)                                                       \
  {                                                                            \
    const int j0 = (jt_) * 64;                                                 \
    const int tp_ = it - (jt_);                                                \
    _Pragma("unroll") for (int i = 0; i < 2; ++i) {                            \
      const int LB = (i * 256 + tid) * 16, row = LB >> 7, rb_ = LB & 127;      \
      const int tb = rb_ ^ ((row & 7) << 4);                                   \
      gload16((const char*)kb + ((size_t)(j0 + row) * NH + h * 64) * 2 + tb,   \
              (char*)Kb[c] + LB);                                              \
      gload16((const char*)vt + ((size_t)(h * 64 + row) * S + j0) * 2 + tb,    \
              (char*)Vb[c] + LB);                                              \
      gload16((const char*)rb +                                                \
                  ((size_t)(S - 1 - 64 * tp_ - row) * NH + h * 64) * 2 + tb,   \
              (char*)Rb[c] + LB);                                              \
    }                                                                          \
  }

  // halfB prologue: stage R(tp0-1) into Rb[1] alongside main-tile stage
  if (half) {
#pragma unroll
    for (int i = 0; i < 2; ++i) {
      const int LB = (i * 256 + tid) * 16, row = LB >> 7, rb_ = LB & 127;
      const int tb = rb_ ^ ((row & 7) << 4);
      gload16((const char*)rb +
                  ((size_t)(S - 1 - 64 * (tp0 - 1) - row) * NH + h * 64) * 2 +
                  tb,
              (char*)Rb[1] + LB);
    }
  }
  AT_STAGE(0, jstart);
  __syncthreads();
  if (half) {  // compute BD tile (tp0-1) from Rb[1]
    f32x4 bd[4];
#pragma unroll
    for (int n = 0; n < 4; ++n) bd[n] = (f32x4){0.f, 0.f, 0.f, 0.f};
#pragma unroll
    for (int ks = 0; ks < 2; ++ks) {
      bf16x8 rf[4];
#pragma unroll
      for (int n = 0; n < 4; ++n)
        rf[n] = ldsT(Rb[1], n * 16 + (l & 15), ks * 64 + (l >> 4) * 16);
      __builtin_amdgcn_s_setprio(1);
#pragma unroll
      for (int n = 0; n < 4; ++n)
        bd[n] = __builtin_amdgcn_mfma_f32_16x16x32_bf16(qrf[ks], rf[n], bd[n],
                                                        0, 0, 0);
      __builtin_amdgcn_s_setprio(0);
    }
    ushort* B = BDb[(tp0 - 1) & 1];
#pragma unroll
    for (int n = 0; n < 4; ++n)
#pragma unroll
      for (int r = 0; r < 4; ++r)
        B[(fr_base + r) * 64 + n * 16 + (l & 15)] = f2bf(bd[n][r]);
    __syncthreads();  // Rb[1] consumed before main-loop prefetch overwrites
  }

  int cur = 0;
  for (int jt = jstart; jt >= jend; --jt) {
    const int tp = it - jt;
    if (jt > jend) AT_STAGE(cur ^ 1, jt - 1);

    // --- BDlag tile tp
    f32x4 bd[4];
#pragma unroll
    for (int n = 0; n < 4; ++n) bd[n] = (f32x4){0.f, 0.f, 0.f, 0.f};
#pragma unroll
    for (int ks = 0; ks < 2; ++ks) {
      bf16x8 rf[4];
#pragma unroll
      for (int n = 0; n < 4; ++n)
        rf[n] = ldsT(Rb[cur], n * 16 + (l & 15), ks * 64 + (l >> 4) * 16);
      __builtin_amdgcn_s_setprio(1);
#pragma unroll
      for (int n = 0; n < 4; ++n)
        bd[n] = __builtin_amdgcn_mfma_f32_16x16x32_bf16(qrf[ks], rf[n], bd[n],
                                                        0, 0, 0);
      __builtin_amdgcn_s_setprio(0);
    }
    {
      ushort* B = BDb[tp & 1];
#pragma unroll
      for (int n = 0; n < 4; ++n)
#pragma unroll
        for (int r = 0; r < 4; ++r)
          B[(fr_base + r) * 64 + n * 16 + (l & 15)] = f2bf(bd[n][r]);
    }

    // --- AC tile
    f32x4 sa[4];
#pragma unroll
    for (int n = 0; n < 4; ++n) sa[n] = (f32x4){0.f, 0.f, 0.f, 0.f};
#pragma unroll
    for (int ks = 0; ks < 2; ++ks) {
      bf16x8 kf[4];
#pragma unroll
      for (int n = 0; n < 4; ++n)
        kf[n] = ldsT(Kb[cur], n * 16 + (l & 15), ks * 64 + (l >> 4) * 16);
      __builtin_amdgcn_s_setprio(1);
#pragma unroll
      for (int n = 0; n < 4; ++n)
        sa[n] = __builtin_amdgcn_mfma_f32_16x16x32_bf16(qwf[ks], kf[n], sa[n],
                                                        0, 0, 0);
      __builtin_amdgcn_s_setprio(0);
    }

    // --- shear BD + mask + online softmax (max only; sum via ones-MFMA)
    const ushort* Bnew = BDb[tp & 1];
    const ushort* Bold = BDb[(tp & 1) ^ 1];
    float p[4][4];
    float rmax[4] = {-1e30f, -1e30f, -1e30f, -1e30f};
#pragma unroll
    for (int n = 0; n < 4; ++n)
#pragma unroll
      for (int r = 0; r < 4; ++r) {
        const int fr = fr_base + r;
        const int jj = n * 16 + (l & 15);
        const int u = 64 + fr - jj;
        const float bdv =
            bf2f((u >= 64) ? Bnew[fr * 64 + (u - 64)] : Bold[fr * 64 + u]);
        float s = (sa[n][r] + bdv) * 0.125f;
        if (tp == 0 && jj > fr) s = -1e30f;
        p[n][r] = s;
        rmax[r] = fmaxf(rmax[r], s);
      }
#pragma unroll
    for (int off = 1; off < 16; off <<= 1)
#pragma unroll
      for (int r = 0; r < 4; ++r)
        rmax[r] = fmaxf(rmax[r], __shfl_xor(rmax[r], off, 64));
    float corr[4];
#pragma unroll
    for (int r = 0; r < 4; ++r) {
      const float mn = fmaxf(m_r[r], rmax[r]);
      corr[r] = __expf(m_r[r] - mn);
      m_r[r] = mn;
    }
#pragma unroll
    for (int n = 0; n < 4; ++n)
#pragma unroll
      for (int r = 0; r < 4; ++r) p[n][r] = __expf(p[n][r] - m_r[r]);
#pragma unroll
    for (int r = 0; r < 4; ++r) acc_l[r] *= corr[r];
#pragma unroll
    for (int n = 0; n < 4; ++n)
#pragma unroll
      for (int r = 0; r < 4; ++r) acc_o[n][r] *= corr[r];

    // --- write P (swizzled, wave-private)
    {
      ushort* P = Pb[w];
#pragma unroll
      for (int n = 0; n < 4; ++n)
#pragma unroll
        for (int r = 0; r < 4; ++r) {
          const int row = (l >> 4) * 4 + r;
          const int colb = (n * 16 + (l & 15)) * 2;
          *(ushort*)((char*)P + row * 128 + (colb ^ ((row & 7) << 4))) =
              f2bf(p[n][r]);
        }
    }

    // --- PV + l accumulation
#pragma unroll
    for (int ks = 0; ks < 2; ++ks) {
      const int prow = l & 15;
      const bf16x8 pf = *(const bf16x8*)(
          (const char*)Pb[w] + prow * 128 +
          ((ks * 64 + (l >> 4) * 16) ^ ((prow & 7) << 4)));
      bf16x8 vf[4];
#pragma unroll
      for (int n = 0; n < 4; ++n)
        vf[n] = ldsT(Vb[cur], n * 16 + (l & 15), ks * 64 + (l >> 4) * 16);
      __builtin_amdgcn_s_setprio(1);
#pragma unroll
      for (int n = 0; n < 4; ++n)
        acc_o[n] = __builtin_amdgcn_mfma_f32_16x16x32_bf16(pf, vf[n], acc_o[n],
                                                           0, 0, 0);
      acc_l = __builtin_amdgcn_mfma_f32_16x16x32_bf16(pf, ones, acc_l, 0, 0, 0);
      __builtin_amdgcn_s_setprio(0);
    }
    __syncthreads();
    cur ^= 1;
  }

  // --- partial epilogue (unnormalized)
#pragma unroll
  for (int n = 0; n < 4; ++n)
#pragma unroll
    for (int r = 0; r < 4; ++r)
      accX[(size_t)(i0 + fr_base + r) * NH + h * 64 + n * 16 + (l & 15)] =
          acc_o[n][r];
  if ((l & 15) == 0)
#pragma unroll
    for (int r = 0; r < 4; ++r) {
      mX[(i0 + fr_base + r) * H + h] = m_r[r];
      lX[(i0 + fr_base + r) * H + h] = acc_l[r];
    }
}

// ---------------------------------------------------------------------------
// combine the two j-half partials -> normalized bf16 attention output
// ---------------------------------------------------------------------------
__global__ __launch_bounds__(256) void combine_halves(
    const float* __restrict__ accA, const float* __restrict__ accB,
    const float* __restrict__ mA, const float* __restrict__ lA,
    const float* __restrict__ mB, const float* __restrict__ lB,
    ushort* __restrict__ ab) {
  const int idx = blockIdx.x * 256 + threadIdx.x;
  const int base = idx * 4;
  const int i = base >> 10;
  const int h = (base & 1023) >> 6;
  const float4 a = *(const float4*)(accA + base);
  const float4 b = *(const float4*)(accB + base);
  const float ma = mA[i * H + h], la = lA[i * H + h];
  const float mb = mB[i * H + h], lb = lB[i * H + h];
  const float M = fmaxf(ma, mb);
  const float ea = __expf(ma - M), eb = __expf(mb - M);
  const float inv = 1.f / (la * ea + lb * eb);
  ushort4 u;
  u.x = f2bf((a.x * ea + b.x * eb) * inv);
  u.y = f2bf((a.y * ea + b.y * eb) * inv);
  u.z = f2bf((a.z * ea + b.z * eb) * inv);
  u.w = f2bf((a.w * ea + b.w * eb) * inv);
  *(ushort4*)(ab + base) = u;
}

// ---------------------------------------------------------------------------
extern "C" void kernel_launch(void* const* d_in, const int* in_sizes, int n_in,
                              void* d_out, int out_size, void* d_ws,
                              size_t ws_size, hipStream_t stream) {
  const float* inq = (const float*)d_in[0];
  const float* pos = (const float*)d_in[1];
  const float* rwb = (const float*)d_in[2];
  const float* rrb = (const float*)d_in[3];
  const float* Wq = (const float*)d_in[4];
  const float* bq = (const float*)d_in[5];
  const float* Wk = (const float*)d_in[6];
  const float* bk = (const float*)d_in[7];
  const float* Wv = (const float*)d_in[8];
  const float* bv = (const float*)d_in[9];
  const float* Wr = (const float*)d_in[10];
  const float* br = (const float*)d_in[11];
  const float* Wo = (const float*)d_in[12];
  const float* bo = (const float*)d_in[13];

  char* ws = (char*)d_ws;
  const size_t MB = 1024 * 1024;
  ushort* A_bf = (ushort*)(ws + 0 * MB);   // [S][F] bf16; combine reuses as ab
  ushort* P_bf = (ushort*)(ws + 4 * MB);   // [S][F] bf16 (dead after R-GEMM)
  ushort* Wqkv = (ushort*)(ws + 8 * MB);   // [3072][1024] stacked (dead post-GEMM)
  ushort* Wrt = (ushort*)(ws + 14 * MB);   // [NH][F]
  ushort* Wot = (ushort*)(ws + 16 * MB);   // [F][NH]
  ushort* qwp = (ushort*)(ws + 18 * MB);   // [S][NH]
  ushort* qrp = (ushort*)(ws + 22 * MB);
  ushort* kbp = (ushort*)(ws + 26 * MB);
  ushort* vtp = (ushort*)(ws + 30 * MB);   // [NH][S]
  ushort* rbp = (ushort*)(ws + 34 * MB);
  // attn-phase aliases (P_bf/Wqkv dead by then):
  float* mlA = (float*)(ws + 4 * MB);      // mA,lA,mB,lB: 4 x 128KB
  float* mA = mlA + 0 * 32768;
  float* lA = mlA + 1 * 32768;
  float* mB = mlA + 2 * 32768;
  float* lB = mlA + 3 * 32768;
  float* accA = (float*)(ws + 6 * MB);     // [S][NH] f32, 8MB (6-14)
  float* accB = (float*)(ws + 38 * MB);    // [S][NH] f32, 8MB (38-46)
  ushort* abp = A_bf;

  conv_bf16<<<2048, 256, 0, stream>>>(inq, A_bf, S * F);
  conv_bf16<<<2048, 256, 0, stream>>>(pos, P_bf, S * F);
  const dim3 gt(16, 16);
  tconv<<<gt, 256, 0, stream>>>(Wq, Wqkv);
  tconv<<<gt, 256, 0, stream>>>(Wk, Wqkv + 1024 * 1024);
  tconv<<<gt, 256, 0, stream>>>(Wv, Wqkv + 2048 * 1024);
  tconv<<<gt, 256, 0, stream>>>(Wr, Wrt);
  tconv<<<gt, 256, 0, stream>>>(Wo, Wot);

  // fused QKV GEMM (N=3072) + R GEMM
  mm_bf16<4><<<dim3(24, 32), 256, 0, stream>>>(A_bf, Wqkv, bq, rwb, rrb, bk, bv,
                                               qwp, qrp, kbp, vtp, S, 3072, F);
  mm_bf16<0><<<dim3(8, 32), 256, 0, stream>>>(P_bf, Wrt, br, nullptr, nullptr,
                                              nullptr, nullptr, rbp, nullptr,
                                              nullptr, nullptr, S, NH, F);

  attn_mfma<<<1024, 256, 0, stream>>>(qwp, qrp, kbp, vtp, rbp, accA, accB, mA,
                                      lA, mB, lB);
  combine_halves<<<2048, 256, 0, stream>>>(accA, accB, mA, lA, mB, lB, abp);

  mm_bf16<3><<<dim3(8, 32), 256, 0, stream>>>(abp, Wot, bo, nullptr, nullptr,
                                              nullptr, nullptr, d_out, nullptr,
                                              nullptr, nullptr, S, F, NH);
}